// Round 14
// baseline (189.754 us; speedup 1.0000x reference)
//
#include <hip/hip_runtime.h>
#include <math.h>

#define BB 16
#define CC 256
#define HH 128
#define WW 128
#define HWSZ (HH * WW)   // 16384

typedef float floatx4 __attribute__((ext_vector_type(4)));

// ---------------------------------------------------------------------------
// Pool over a 4-batch QUARTER. Tile = 128 px; block = 32 f4-groups x 8
// channel-splits (32 ch/thread). Grid 512 = 4 batches x 128 tiles.
// Caching loads: x-quarter (67 MB) lands in L3 for this quarter's convmul.
// ---------------------------------------------------------------------------
__global__ __launch_bounds__(256) void pool_q_kernel(const float* __restrict__ x,
                                                     float* __restrict__ avg_out,
                                                     float* __restrict__ max_out,
                                                     int b0) {
    const int tf4   = threadIdx.x & 31;   // f4 group within 128-px tile
    const int split = threadIdx.x >> 5;   // 0..7 channel split
    const int tile  = blockIdx.x;         // 0..511
    const int b     = b0 + (tile >> 7);   // 128 tiles per batch
    const int hw    = (tile & 127) * 128 + tf4 * 4;

    const float* xb = x + (size_t)(b * CC + split * 32) * HWSZ + hw;

    float4 s = make_float4(0.f, 0.f, 0.f, 0.f);
    float4 m = make_float4(-INFINITY, -INFINITY, -INFINITY, -INFINITY);

    #pragma unroll 8
    for (int i = 0; i < 32; ++i) {
        float4 v = *(const float4*)(xb + (size_t)i * HWSZ);
        s.x += v.x; s.y += v.y; s.z += v.z; s.w += v.w;
        m.x = fmaxf(m.x, v.x); m.y = fmaxf(m.y, v.y);
        m.z = fmaxf(m.z, v.z); m.w = fmaxf(m.w, v.w);
    }

    __shared__ float4 sS[8][32];
    __shared__ float4 sM[8][32];
    sS[split][tf4] = s;
    sM[split][tf4] = m;
    __syncthreads();

    for (int off = 4; off >= 1; off >>= 1) {
        if (split < off) {
            float4 a  = sS[split][tf4], b2 = sS[split + off][tf4];
            a.x += b2.x; a.y += b2.y; a.z += b2.z; a.w += b2.w;
            sS[split][tf4] = a;
            float4 ma = sM[split][tf4], mb = sM[split + off][tf4];
            ma.x = fmaxf(ma.x, mb.x); ma.y = fmaxf(ma.y, mb.y);
            ma.z = fmaxf(ma.z, mb.z); ma.w = fmaxf(ma.w, mb.w);
            sM[split][tf4] = ma;
        }
        __syncthreads();
    }

    if (split == 0) {
        float4 a = sS[0][tf4];
        const float inv = 1.0f / CC;
        a.x *= inv; a.y *= inv; a.z *= inv; a.w *= inv;
        *(float4*)(avg_out + (size_t)b * HWSZ + hw) = a;
        *(float4*)(max_out + (size_t)b * HWSZ + hw) = sM[0][tf4];
    }
}

// ---------------------------------------------------------------------------
// Conv+sigmoid+multiply over a 4-batch QUARTER. Block = (2-row strip,
// channel-half); grid 512. NORMAL loads (all L3 hits on the quarter) and
// NORMAL allocating stores — safe now because x-quarter + out-quarter =
// 134 MB < 256 MB L3, so out allocations evict only dead lines. Dirty out
// flushes during the NEXT quarter's pool (overlap) or off-clock (last one).
// ---------------------------------------------------------------------------
__global__ __launch_bounds__(256) void convmul_q_kernel(const float* __restrict__ x,
                                                        const float* __restrict__ avg_p,
                                                        const float* __restrict__ max_p,
                                                        const float* __restrict__ wgt,
                                                        float* __restrict__ out,
                                                        int b0) {
    __shared__ float sw[98];
    __shared__ float sMl[256];

    const int tid = threadIdx.x;
    if (tid < 98) sw[tid] = wgt[tid];
    __syncthreads();

    const int bid   = blockIdx.x;        // 0..511
    const int hc    = bid & 1;           // channel half
    const int strip = bid >> 1;          // 0..255
    const int b     = b0 + (strip >> 6); // 64 strips per batch
    const int h0    = (strip & 63) * 2;  // strip's first row

    // ---- phase a: conv + sigmoid for this strip's 256 pixels ----
    {
        const int hl = tid >> 7;
        const int w  = tid & 127;
        const int h  = h0 + hl;
        const float* ap = avg_p + (size_t)b * HWSZ;
        const float* mp = max_p + (size_t)b * HWSZ;

        float acc = 0.f;
        #pragma unroll
        for (int kh = 0; kh < 7; ++kh) {
            const int hh = h + kh - 3;
            if (hh < 0 || hh >= HH) continue;
            #pragma unroll
            for (int kw = 0; kw < 7; ++kw) {
                const int ww2 = w + kw - 3;
                if (ww2 < 0 || ww2 >= WW) continue;
                const int off = hh * WW + ww2;
                acc += ap[off] * sw[kh * 7 + kw];
                acc += mp[off] * sw[49 + kh * 7 + kw];
            }
        }
        sMl[tid] = 1.0f / (1.0f + expf(-acc));
    }
    __syncthreads();

    // ---- phase b: out = x * M over this block's 128 channels ----
    const int g    = tid & 63;            // f4 group within strip
    const int csub = tid >> 6;            // 0..3
    const floatx4 mv = ((const floatx4*)sMl)[g];

    const size_t base = (size_t)b * CC * HWSZ
                      + (size_t)(hc * 128 + csub) * HWSZ
                      + (size_t)h0 * WW + (size_t)g * 4;
    const float* xp = x + base;
    float*       op = out + base;

    #pragma unroll 8
    for (int c = 0; c < 32; ++c) {
        const size_t coff = (size_t)c * 4 * HWSZ;
        floatx4 xv = *(const floatx4*)(xp + coff);   // normal load (L3 hit)
        *(floatx4*)(op + coff) = xv * mv;            // NORMAL store (allocate, flush later)
    }
}

extern "C" void kernel_launch(void* const* d_in, const int* in_sizes, int n_in,
                              void* d_out, int out_size, void* d_ws, size_t ws_size,
                              hipStream_t stream) {
    const float* x   = (const float*)d_in[0];
    const float* wgt = (const float*)d_in[1];
    float* out = (float*)d_out;

    float* avg_p = (float*)d_ws;                   // 1 MB
    float* max_p = avg_p + (size_t)BB * HWSZ;      // 1 MB

    // Four batch-quarters: pool-k then convmul-k. Working set per quarter
    // (x 67 MB + out 67 MB) fits L3 -> allocating stores never evict unread x.
    for (int q = 0; q < 4; ++q) {
        pool_q_kernel<<<512, 256, 0, stream>>>(x, avg_p, max_p, q * 4);
        convmul_q_kernel<<<512, 256, 0, stream>>>(x, avg_p, max_p, wgt, out, q * 4);
    }
}

// Round 15
// 142.517 us; speedup vs baseline: 1.3315x; 1.3315x over previous
//
#include <hip/hip_runtime.h>
#include <math.h>

#define BB 16
#define CC 256
#define HH 128
#define WW 128
#define HWSZ (HH * WW)   // 16384

typedef float floatx4 __attribute__((ext_vector_type(4)));

// ---------------------------------------------------------------------------
// RESTORED BEST (R11, 142.1 us — within ~1% of the measured-floor model:
// pool 268 MB @ ~7 TB/s + convmul 536 MB mixed @ ~5.25 TB/s).
//
// Kernel 1: channel-wise avg & max pool. Caching loads ON PURPOSE: x must
// land in L3 so convmul's re-read is served from Infinity Cache (R4 PMC
// proof: FETCH = 266 MB total — x fetched from HBM exactly once).
// ---------------------------------------------------------------------------
__global__ __launch_bounds__(256) void pool_kernel(const float* __restrict__ x,
                                                   float* __restrict__ avg_out,
                                                   float* __restrict__ max_out) {
    const int tf4   = threadIdx.x & 63;   // f4 group within 256-px tile
    const int split = threadIdx.x >> 6;   // 0..3 channel split
    const int p0    = blockIdx.x * 256;   // first pixel of tile
    const int b     = p0 >> 14;           // tiles never straddle batch
    const int hw    = (p0 & (HWSZ - 1)) + tf4 * 4;

    const float* xb = x + (size_t)b * CC * HWSZ + hw;

    float4 s = make_float4(0.f, 0.f, 0.f, 0.f);
    float4 m = make_float4(-INFINITY, -INFINITY, -INFINITY, -INFINITY);

    const int c0 = split * 64;
    #pragma unroll 8
    for (int i = 0; i < 64; ++i) {
        float4 v = *(const float4*)(xb + (size_t)(c0 + i) * HWSZ);
        s.x += v.x; s.y += v.y; s.z += v.z; s.w += v.w;
        m.x = fmaxf(m.x, v.x); m.y = fmaxf(m.y, v.y);
        m.z = fmaxf(m.z, v.z); m.w = fmaxf(m.w, v.w);
    }

    __shared__ float4 sS[4][64];
    __shared__ float4 sM[4][64];
    sS[split][tf4] = s;
    sM[split][tf4] = m;
    __syncthreads();

    for (int off = 2; off >= 1; off >>= 1) {
        if (split < off) {
            float4 a  = sS[split][tf4], b2 = sS[split + off][tf4];
            a.x += b2.x; a.y += b2.y; a.z += b2.z; a.w += b2.w;
            sS[split][tf4] = a;
            float4 ma = sM[split][tf4], mb = sM[split + off][tf4];
            ma.x = fmaxf(ma.x, mb.x); ma.y = fmaxf(ma.y, mb.y);
            ma.z = fmaxf(ma.z, mb.z); ma.w = fmaxf(ma.w, mb.w);
            sM[split][tf4] = ma;
        }
        __syncthreads();
    }

    if (split == 0) {
        float4 a = sS[0][tf4];
        const float inv = 1.0f / CC;
        a.x *= inv; a.y *= inv; a.z *= inv; a.w *= inv;
        *(float4*)(avg_out + (size_t)b * HWSZ + hw) = a;
        *(float4*)(max_out + (size_t)b * HWSZ + hw) = sM[0][tf4];
    }
}

// ---------------------------------------------------------------------------
// Kernel 2: conv(7x7)+sigmoid fused with broadcast multiply.
// Winning policy cell (R5/R9/R11/R13 matrix): NORMAL loads (L3 hits on warm
// x, full-rate read path) + NONTEMPORAL stores (out must not allocate in L3
// and evict unread x — allocating stores cost ~30 us of refetch, R9/R13).
// ---------------------------------------------------------------------------
__global__ __launch_bounds__(256) void convmul_kernel(const float* __restrict__ x,
                                                      const float* __restrict__ avg_p,
                                                      const float* __restrict__ max_p,
                                                      const float* __restrict__ wgt,
                                                      float* __restrict__ out) {
    __shared__ float sw[98];
    __shared__ float sMl[256];

    const int tid = threadIdx.x;
    if (tid < 98) sw[tid] = wgt[tid];
    __syncthreads();

    const int strip = blockIdx.x;        // 0..1023
    const int b     = strip >> 6;        // 64 strips per batch
    const int h0    = (strip & 63) * 2;  // strip's first row

    // ---- phase a: conv + sigmoid for this strip's 256 pixels ----
    {
        const int hl = tid >> 7;
        const int w  = tid & 127;
        const int h  = h0 + hl;
        const float* ap = avg_p + (size_t)b * HWSZ;
        const float* mp = max_p + (size_t)b * HWSZ;

        float acc = 0.f;
        #pragma unroll
        for (int kh = 0; kh < 7; ++kh) {
            const int hh = h + kh - 3;
            if (hh < 0 || hh >= HH) continue;
            #pragma unroll
            for (int kw = 0; kw < 7; ++kw) {
                const int ww2 = w + kw - 3;
                if (ww2 < 0 || ww2 >= WW) continue;
                const int off = hh * WW + ww2;
                acc += ap[off] * sw[kh * 7 + kw];
                acc += mp[off] * sw[49 + kh * 7 + kw];
            }
        }
        sMl[tid] = 1.0f / (1.0f + expf(-acc));
    }
    __syncthreads();

    // ---- phase b: out = x * M over all 256 channels ----
    const int g    = tid & 63;            // f4 group within strip (64 x 4 px)
    const int csub = tid >> 6;            // 0..3
    const floatx4 mv = ((const floatx4*)sMl)[g];

    const size_t base = (size_t)b * CC * HWSZ + (size_t)h0 * WW + (size_t)g * 4;
    const float* xp = x + base;
    float*       op = out + base;

    #pragma unroll 4
    for (int c = 0; c < 64; ++c) {
        const size_t coff = (size_t)(c * 4 + csub) * HWSZ;
        floatx4 xv = *(const floatx4*)(xp + coff);           // normal load (L3 hit)
        __builtin_nontemporal_store(xv * mv, (floatx4*)(op + coff));  // NT store
    }
}

extern "C" void kernel_launch(void* const* d_in, const int* in_sizes, int n_in,
                              void* d_out, int out_size, void* d_ws, size_t ws_size,
                              hipStream_t stream) {
    const float* x   = (const float*)d_in[0];
    const float* wgt = (const float*)d_in[1];
    float* out = (float*)d_out;

    float* avg_p = (float*)d_ws;                   // 1 MB
    float* max_p = avg_p + (size_t)BB * HWSZ;      // 1 MB

    pool_kernel<<<1024, 256, 0, stream>>>(x, avg_p, max_p);
    convmul_kernel<<<1024, 256, 0, stream>>>(x, avg_p, max_p, wgt, out);
}